// Round 3
// baseline (1267.185 us; speedup 1.0000x reference)
//
#include <hip/hip_runtime.h>

// ---------------- constants ----------------
#define B_SZ   512
#define K_SZ   512
#define N_CLS  100000
#define NB     1563          // (N_CLS+63)/64 column panels
#define NGRP   128           // fallback grouped-partial slots
#define SCALE_ 64.0f
#define MSLOPE 0.0035f       // (0.8-0.45)/(110-10)
#define L_A_   10.0f
#define U_A_   110.0f

typedef unsigned short u16;
typedef short bf16x8 __attribute__((ext_vector_type(8)));
typedef float f32x4 __attribute__((ext_vector_type(4)));
typedef u16   u16x4 __attribute__((ext_vector_type(4)));

static __device__ inline u16 f2bf(float f) {
    unsigned int u = __float_as_uint(f);
    unsigned int r = (u + 0x7FFFu + ((u >> 16) & 1u)) >> 16;  // RNE
    return (u16)r;
}

// ---------------- kernel A: per-row prep ----------------
__global__ __launch_bounds__(256) void prep_x(
    const float* __restrict__ x, u16* __restrict__ xu,
    float* __restrict__ cosm, float* __restrict__ sinm,
    float* __restrict__ gterm)
{
    int b = blockIdx.x;
    int tid = threadIdx.x;  // 256 threads, 2 elems each
    float v0 = x[b * K_SZ + tid];
    float v1 = x[b * K_SZ + 256 + tid];
    float s = v0 * v0 + v1 * v1;
    #pragma unroll
    for (int off = 32; off; off >>= 1) s += __shfl_down(s, off);
    __shared__ float red[4];
    if ((tid & 63) == 0) red[tid >> 6] = s;
    __syncthreads();
    float tot = red[0] + red[1] + red[2] + red[3];
    float norm = sqrtf(tot);
    float inv = 1.0f / norm;              // x_unit uses UNclamped norm
    xu[b * K_SZ + tid]       = f2bf(v0 * inv);
    xu[b * K_SZ + 256 + tid] = f2bf(v1 * inv);
    if (tid == 0) {
        float cl = fminf(fmaxf(norm, L_A_), U_A_);   // clamped norm
        float ada = MSLOPE * (cl - L_A_) + 0.45f;
        cosm[b] = cosf(ada);
        sinm[b] = sinf(ada);
        gterm[b] = cl * (1.0f / (U_A_ * U_A_)) + 1.0f / cl;
    }
}

// ---------------- kernel B: fused GEMM + wnorm + margin + partial sumexp ----
// BM=512 (whole batch) x BN=64 cols per block, BK=32, 8 waves (wave = 64 rows).
// A fragments read straight from global (xu is 512KB, L2-resident) -> LDS is
// only the double-buffered B panel (8KB) => 4 blocks/CU, 32 waves/CU.
// Per-column sum(w^2) fused into B staging. Row partial-sums written as plain
// coalesced stores (mode=1: rowpart[bid][row]; mode=0: grouped atomics).
__global__ __launch_bounds__(512, 8) void gemm_softmax(
    const u16* __restrict__ xu, const float* __restrict__ W,
    const float* __restrict__ cosm, const float* __restrict__ sinm,
    const int* __restrict__ target,
    float* __restrict__ rowpart, float* __restrict__ tgtl, int full_mode)
{
    __shared__ u16 Bb[2][4][64][8];    // 8 KB (buf, k_oct, col, 8k)
    __shared__ float sumsq_s[64];
    __shared__ float invw_s[64];
    __shared__ float rowbuf[512];

    const int tid  = threadIdx.x;
    const int lane = tid & 63;
    const int wid  = tid >> 6;          // 0..7
    const int n0   = blockIdx.x * 64;

    // B staging mapping: thread -> (col = lane, ko = wid&3, jh = wid>>2)
    const int bko = wid & 3;
    const int bjh = wid >> 2;
    const int gcol = min(n0 + lane, N_CLS - 1);
    const float* wp = W + (size_t)(bko * 8 + bjh * 4) * N_CLS + (size_t)gcol;

    const int sel = lane & 15, ko = lane >> 4;
    const u16* abase = xu + (size_t)(wid * 64 + sel) * K_SZ + ko * 8;

    float ss = 0.f;
    f32x4 acc[4][4] = {};

    // ---------- prologue: stage B kt=0 ----------
    {
        float bv[4];
        #pragma unroll
        for (int j = 0; j < 4; ++j) bv[j] = wp[(size_t)j * N_CLS];
        u16x4 bw;
        #pragma unroll
        for (int j = 0; j < 4; ++j) { ss += bv[j] * bv[j]; bw[j] = f2bf(bv[j]); }
        *reinterpret_cast<u16x4*>(&Bb[0][bko][lane][bjh * 4]) = bw;
    }
    __syncthreads();

    // ---------- main loop ----------
    for (int kt = 0; kt < 16; ++kt) {
        const int cur = kt & 1, nxt = cur ^ 1;
        float bv[4];
        if (kt < 15) {
            #pragma unroll
            for (int j = 0; j < 4; ++j)
                bv[j] = wp[(size_t)((kt + 1) * 32 + j) * N_CLS];
        }

        bf16x8 a[4], b[4];
        #pragma unroll
        for (int m = 0; m < 4; ++m)
            a[m] = *reinterpret_cast<const bf16x8*>(abase + (size_t)m * 16 * K_SZ + kt * 32);
        #pragma unroll
        for (int n = 0; n < 4; ++n)
            b[n] = *reinterpret_cast<const bf16x8*>(&Bb[cur][ko][n * 16 + sel][0]);
        #pragma unroll
        for (int m = 0; m < 4; ++m)
            #pragma unroll
            for (int n = 0; n < 4; ++n)
                acc[m][n] = __builtin_amdgcn_mfma_f32_16x16x32_bf16(
                    a[m], b[n], acc[m][n], 0, 0, 0);

        if (kt < 15) {
            u16x4 bw;
            #pragma unroll
            for (int j = 0; j < 4; ++j) { ss += bv[j] * bv[j]; bw[j] = f2bf(bv[j]); }
            *reinterpret_cast<u16x4*>(&Bb[nxt][bko][lane][bjh * 4]) = bw;
        }
        __syncthreads();
    }

    // ---------- per-column inv norm ----------
    if (tid < 64) sumsq_s[tid] = 0.f;
    __syncthreads();
    atomicAdd(&sumsq_s[lane], ss);      // LDS atomics, 8 threads/col
    __syncthreads();
    if (tid < 64) invw_s[tid] = rsqrtf(sumsq_s[tid]);
    __syncthreads();

    // ---------- epilogue: margin + exp + row partial sums ----------
    const int cloc = lane & 15;
    const int rgrp = lane >> 4;
    float iw[4]; int cols[4];
    #pragma unroll
    for (int n = 0; n < 4; ++n) {
        cols[n] = n0 + n * 16 + cloc;
        iw[n] = invw_s[n * 16 + cloc];
    }
    #pragma unroll
    for (int m = 0; m < 4; ++m) {
        #pragma unroll
        for (int j = 0; j < 4; ++j) {
            int row = wid * 64 + m * 16 + rgrp * 4 + j;
            float cm = cosm[row], smv = sinm[row];
            int tg = target[row];
            float s = 0.f;
            #pragma unroll
            for (int n = 0; n < 4; ++n) {
                if (cols[n] < N_CLS) {
                    float cosv = acc[m][n][j] * iw[n];
                    cosv = fminf(fmaxf(cosv, -1.f), 1.f);
                    float logit = SCALE_ * cosv;
                    if (cols[n] == tg) {
                        float st = sqrtf(fmaxf(0.f, 1.f - cosv * cosv));
                        float cmm = (cosv > 0.f) ? (cosv * cm - st * smv) : cosv;
                        logit = SCALE_ * cmm;
                        tgtl[row] = logit;   // unique writer per row
                    }
                    s += __expf(logit - SCALE_);
                }
            }
            #pragma unroll
            for (int off = 1; off < 16; off <<= 1) s += __shfl_xor(s, off);
            if (cloc == 0) rowbuf[row] = s;
        }
    }
    __syncthreads();
    // coalesced per-block partial write (or grouped atomic fallback)
    if (full_mode) {
        rowpart[(size_t)blockIdx.x * B_SZ + tid] = rowbuf[tid];
    } else {
        atomicAdd(&rowpart[(size_t)(blockIdx.x & (NGRP - 1)) * B_SZ + tid],
                  rowbuf[tid]);
    }
}

// ---------------- kernel C: reduce row partials ----------------
__global__ __launch_bounds__(512) void reduce_rows(
    const float* __restrict__ rowpart, float* __restrict__ rowsum, int ng)
{
    int row = threadIdx.x;
    int chunk = (ng + 31) / 32;
    int b0 = blockIdx.x * chunk;
    int b1 = min(b0 + chunk, ng);
    float s = 0.f;
    for (int b = b0; b < b1; ++b)
        s += rowpart[(size_t)b * B_SZ + row];
    atomicAdd(&rowsum[row], s);   // 32 atomics/row, well spread
}

// ---------------- kernel D: finalize ----------------
__global__ __launch_bounds__(512) void finalize(
    const float* __restrict__ rowsum, const float* __restrict__ tgtl,
    const float* __restrict__ gterm, float* __restrict__ out)
{
    int tid = threadIdx.x;
    float v = 0.f;
    if (tid < B_SZ) {
        float ce = SCALE_ + logf(rowsum[tid]) - tgtl[tid];
        v = ce + 20.f * gterm[tid];
    }
    #pragma unroll
    for (int off = 32; off; off >>= 1) v += __shfl_down(v, off);
    __shared__ float red[8];
    if ((tid & 63) == 0) red[tid >> 6] = v;
    __syncthreads();
    if (tid == 0) {
        float t = 0.f;
        #pragma unroll
        for (int i = 0; i < 8; ++i) t += red[i];
        out[0] = t / (float)B_SZ;
    }
}

// ---------------- launch ----------------
extern "C" void kernel_launch(void* const* d_in, const int* in_sizes, int n_in,
                              void* d_out, int out_size, void* d_ws, size_t ws_size,
                              hipStream_t stream)
{
    const float* x      = (const float*)d_in[0];
    const int*   target = (const int*)d_in[1];
    const float* W      = (const float*)d_in[2];
    float* out = (float*)d_out;

    char* ws = (char*)d_ws;
    u16*   xu      = (u16*)(ws);                    // 512*512*2 = 524288
    float* cosm    = (float*)(ws + 524288);
    float* sinm    = (float*)(ws + 526336);
    float* gterm   = (float*)(ws + 528384);
    float* tgtl    = (float*)(ws + 530432);
    float* rowsum  = (float*)(ws + 532480);
    float* rowpart = (float*)(ws + 534528);
    const size_t need_full = 534528 + (size_t)NB * B_SZ * 4;

    int full_mode = (ws_size >= need_full) ? 1 : 0;
    int ng = full_mode ? NB : NGRP;

    hipMemsetAsync(rowsum, 0, B_SZ * sizeof(float), stream);
    if (!full_mode)
        hipMemsetAsync(rowpart, 0, (size_t)NGRP * B_SZ * sizeof(float), stream);

    prep_x<<<B_SZ, 256, 0, stream>>>(x, xu, cosm, sinm, gterm);
    gemm_softmax<<<NB, 512, 0, stream>>>(xu, W, cosm, sinm, target,
                                         rowpart, tgtl, full_mode);
    reduce_rows<<<32, 512, 0, stream>>>(rowpart, rowsum, ng);
    finalize<<<1, 512, 0, stream>>>(rowsum, tgtl, gterm, out);
}

// Round 4
// 481.634 us; speedup vs baseline: 2.6310x; 2.6310x over previous
//
#include <hip/hip_runtime.h>

// ---------------- constants ----------------
#define B_SZ   512
#define K_SZ   512
#define N_CLS  100000
#define NB     1563          // (N_CLS+63)/64 column panels
#define NGRP   128           // fallback grouped-partial slots
#define SCALE_ 64.0f
#define MSLOPE 0.0035f       // (0.8-0.45)/(110-10)
#define L_A_   10.0f
#define U_A_   110.0f

typedef unsigned short u16;
typedef short bf16x8 __attribute__((ext_vector_type(8)));
typedef float f32x4 __attribute__((ext_vector_type(4)));
typedef u16   u16x4 __attribute__((ext_vector_type(4)));

static __device__ inline u16 f2bf(float f) {
    unsigned int u = __float_as_uint(f);
    unsigned int r = (u + 0x7FFFu + ((u >> 16) & 1u)) >> 16;  // RNE
    return (u16)r;
}

static __device__ inline void gl_lds16(const void* g, void* l) {
    __builtin_amdgcn_global_load_lds(
        (const __attribute__((address_space(1))) void*)g,
        (__attribute__((address_space(3))) void*)l, 16, 0, 0);
}

// ---------------- kernel A: per-row prep ----------------
__global__ __launch_bounds__(256) void prep_x(
    const float* __restrict__ x, u16* __restrict__ xu,
    float* __restrict__ cosm, float* __restrict__ sinm,
    float* __restrict__ gterm)
{
    int b = blockIdx.x;
    int tid = threadIdx.x;  // 256 threads, 2 elems each
    float v0 = x[b * K_SZ + tid];
    float v1 = x[b * K_SZ + 256 + tid];
    float s = v0 * v0 + v1 * v1;
    #pragma unroll
    for (int off = 32; off; off >>= 1) s += __shfl_down(s, off);
    __shared__ float red[4];
    if ((tid & 63) == 0) red[tid >> 6] = s;
    __syncthreads();
    float tot = red[0] + red[1] + red[2] + red[3];
    float norm = sqrtf(tot);
    float inv = 1.0f / norm;              // x_unit uses UNclamped norm
    xu[b * K_SZ + tid]       = f2bf(v0 * inv);
    xu[b * K_SZ + 256 + tid] = f2bf(v1 * inv);
    if (tid == 0) {
        float cl = fminf(fmaxf(norm, L_A_), U_A_);   // clamped norm
        float ada = MSLOPE * (cl - L_A_) + 0.45f;
        cosm[b] = cosf(ada);
        sinm[b] = sinf(ada);
        gterm[b] = cl * (1.0f / (U_A_ * U_A_)) + 1.0f / cl;
    }
}

// ---------------- kernel B: fused GEMM + wnorm + margin + partial sumexp ----
// BM=512 (whole batch) x BN=64 cols, BK=32, 8 waves (wave = 64 rows).
// A staged coalesced: wave-inst = 16 rows x 64B full lines; LDS dest linear
// (global_load_lds constraint); k-slot XOR swizzle applied on the GLOBAL
// source so swizzled ds_read_b128 fragment reads are ~2-way (free).
// W read once; per-column sum(w^2) fused into B reg-staging.
// Row partials: plain coalesced store (full mode) or grouped atomics.
__global__ __launch_bounds__(512, 4) void gemm_softmax(
    const u16* __restrict__ xu, const float* __restrict__ W,
    const float* __restrict__ cosm, const float* __restrict__ sinm,
    const int* __restrict__ target,
    float* __restrict__ rowpart, float* __restrict__ tgtl, int full_mode)
{
    __shared__ u16 As[2][512][32];     // 64 KB (buf, row, 4 slots x 8 bf16)
    __shared__ u16 Bb[2][4][64][8];    // 8 KB  (buf, k_oct, col, 8k)
    __shared__ float sumsq_s[64];
    __shared__ float invw_s[64];
    __shared__ float rowbuf[512];

    const int tid  = threadIdx.x;
    const int lane = tid & 63;
    const int wid  = tid >> 6;          // 0..7
    const int n0   = blockIdx.x * 64;

    // B staging mapping: col = lane, ko = wid&3, jh = wid>>2
    const int bko = wid & 3;
    const int bjh = wid >> 2;
    const int gcol = min(n0 + lane, N_CLS - 1);
    const float* wp = W + (size_t)(bko * 8 + bjh * 4) * N_CLS + (size_t)gcol;

    // A staging mapping: inst i covers rows wid*64+i*16 .. +15 (4 lanes/row)
    const int arow = lane >> 2;         // row within 16-row group
    const int aslot = lane & 3;         // 16B slot within row

    // fragment mapping
    const int sel = lane & 15, fko = lane >> 4;

    float ss = 0.f;
    f32x4 acc[4][4] = {};

    // ---------- prologue: stage kt=0 into buf 0 ----------
    {
        #pragma unroll
        for (int i = 0; i < 4; ++i) {
            int row = wid * 64 + i * 16 + arow;
            int ko  = aslot ^ ((row >> 1) & 3);      // inverse swizzle on src
            gl_lds16(xu + (size_t)row * K_SZ + ko * 8,
                     &As[0][wid * 64 + i * 16][0]);
        }
        float bv[4];
        #pragma unroll
        for (int j = 0; j < 4; ++j) bv[j] = wp[(size_t)j * N_CLS];
        u16x4 bw;
        #pragma unroll
        for (int j = 0; j < 4; ++j) { ss += bv[j] * bv[j]; bw[j] = f2bf(bv[j]); }
        *reinterpret_cast<u16x4*>(&Bb[0][bko][lane][bjh * 4]) = bw;
    }
    __syncthreads();

    // ---------- main loop ----------
    for (int kt = 0; kt < 16; ++kt) {
        const int cur = kt & 1, nxt = cur ^ 1;
        float bv[4];
        if (kt < 15) {
            #pragma unroll
            for (int i = 0; i < 4; ++i) {
                int row = wid * 64 + i * 16 + arow;
                int ko  = aslot ^ ((row >> 1) & 3);
                gl_lds16(xu + (size_t)row * K_SZ + (kt + 1) * 32 + ko * 8,
                         &As[nxt][wid * 64 + i * 16][0]);
            }
            #pragma unroll
            for (int j = 0; j < 4; ++j)
                bv[j] = wp[(size_t)((kt + 1) * 32 + j) * N_CLS];
        }

        // MFMA on current buffers
        {
            bf16x8 a[4], b[4];
            #pragma unroll
            for (int m = 0; m < 4; ++m) {
                int row = wid * 64 + m * 16 + sel;
                int s = fko ^ ((row >> 1) & 3);
                a[m] = *reinterpret_cast<const bf16x8*>(&As[cur][row][s * 8]);
            }
            #pragma unroll
            for (int n = 0; n < 4; ++n)
                b[n] = *reinterpret_cast<const bf16x8*>(
                    &Bb[cur][fko][n * 16 + sel][0]);
            #pragma unroll
            for (int m = 0; m < 4; ++m)
                #pragma unroll
                for (int n = 0; n < 4; ++n)
                    acc[m][n] = __builtin_amdgcn_mfma_f32_16x16x32_bf16(
                        a[m], b[n], acc[m][n], 0, 0, 0);
        }

        if (kt < 15) {
            u16x4 bw;
            #pragma unroll
            for (int j = 0; j < 4; ++j) { ss += bv[j] * bv[j]; bw[j] = f2bf(bv[j]); }
            *reinterpret_cast<u16x4*>(&Bb[nxt][bko][lane][bjh * 4]) = bw;
        }
        __syncthreads();
    }

    // ---------- per-column inv norm ----------
    if (tid < 64) sumsq_s[tid] = 0.f;
    __syncthreads();
    atomicAdd(&sumsq_s[lane], ss);      // LDS atomics, 8 threads/col
    __syncthreads();
    if (tid < 64) invw_s[tid] = rsqrtf(sumsq_s[tid]);
    __syncthreads();

    // ---------- epilogue: margin + exp + row partial sums ----------
    const int cloc = lane & 15;
    const int rgrp = lane >> 4;
    float iw[4]; int cols[4];
    #pragma unroll
    for (int n = 0; n < 4; ++n) {
        cols[n] = n0 + n * 16 + cloc;
        iw[n] = invw_s[n * 16 + cloc];
    }
    #pragma unroll
    for (int m = 0; m < 4; ++m) {
        #pragma unroll
        for (int j = 0; j < 4; ++j) {
            int row = wid * 64 + m * 16 + rgrp * 4 + j;
            float cm = cosm[row], smv = sinm[row];
            int tg = target[row];
            float s = 0.f;
            #pragma unroll
            for (int n = 0; n < 4; ++n) {
                if (cols[n] < N_CLS) {
                    float cosv = acc[m][n][j] * iw[n];
                    cosv = fminf(fmaxf(cosv, -1.f), 1.f);
                    float logit = SCALE_ * cosv;
                    if (cols[n] == tg) {
                        float st = sqrtf(fmaxf(0.f, 1.f - cosv * cosv));
                        float cmm = (cosv > 0.f) ? (cosv * cm - st * smv) : cosv;
                        logit = SCALE_ * cmm;
                        tgtl[row] = logit;   // unique writer per row
                    }
                    s += __expf(logit - SCALE_);
                }
            }
            #pragma unroll
            for (int off = 1; off < 16; off <<= 1) s += __shfl_xor(s, off);
            if (cloc == 0) rowbuf[row] = s;
        }
    }
    __syncthreads();
    if (full_mode) {
        rowpart[(size_t)blockIdx.x * B_SZ + tid] = rowbuf[tid];
    } else {
        atomicAdd(&rowpart[(size_t)(blockIdx.x & (NGRP - 1)) * B_SZ + tid],
                  rowbuf[tid]);
    }
}

// ---------------- kernel C: reduce row partials ----------------
__global__ __launch_bounds__(512) void reduce_rows(
    const float* __restrict__ rowpart, float* __restrict__ rowsum, int ng)
{
    int row = threadIdx.x;
    int chunk = (ng + 31) / 32;
    int b0 = blockIdx.x * chunk;
    int b1 = min(b0 + chunk, ng);
    float s = 0.f;
    for (int b = b0; b < b1; ++b)
        s += rowpart[(size_t)b * B_SZ + row];
    atomicAdd(&rowsum[row], s);   // 32 atomics/row, well spread
}

// ---------------- kernel D: finalize ----------------
__global__ __launch_bounds__(512) void finalize(
    const float* __restrict__ rowsum, const float* __restrict__ tgtl,
    const float* __restrict__ gterm, float* __restrict__ out)
{
    int tid = threadIdx.x;
    float v = 0.f;
    if (tid < B_SZ) {
        float ce = SCALE_ + logf(rowsum[tid]) - tgtl[tid];
        v = ce + 20.f * gterm[tid];
    }
    #pragma unroll
    for (int off = 32; off; off >>= 1) v += __shfl_down(v, off);
    __shared__ float red[8];
    if ((tid & 63) == 0) red[tid >> 6] = v;
    __syncthreads();
    if (tid == 0) {
        float t = 0.f;
        #pragma unroll
        for (int i = 0; i < 8; ++i) t += red[i];
        out[0] = t / (float)B_SZ;
    }
}

// ---------------- launch ----------------
extern "C" void kernel_launch(void* const* d_in, const int* in_sizes, int n_in,
                              void* d_out, int out_size, void* d_ws, size_t ws_size,
                              hipStream_t stream)
{
    const float* x      = (const float*)d_in[0];
    const int*   target = (const int*)d_in[1];
    const float* W      = (const float*)d_in[2];
    float* out = (float*)d_out;

    char* ws = (char*)d_ws;
    u16*   xu      = (u16*)(ws);                    // 512*512*2 = 524288
    float* cosm    = (float*)(ws + 524288);
    float* sinm    = (float*)(ws + 526336);
    float* gterm   = (float*)(ws + 528384);
    float* tgtl    = (float*)(ws + 530432);
    float* rowsum  = (float*)(ws + 532480);
    float* rowpart = (float*)(ws + 534528);
    const size_t need_full = 534528 + (size_t)NB * B_SZ * 4;

    int full_mode = (ws_size >= need_full) ? 1 : 0;
    int ng = full_mode ? NB : NGRP;

    hipMemsetAsync(rowsum, 0, B_SZ * sizeof(float), stream);
    if (!full_mode)
        hipMemsetAsync(rowpart, 0, (size_t)NGRP * B_SZ * sizeof(float), stream);

    prep_x<<<B_SZ, 256, 0, stream>>>(x, xu, cosm, sinm, gterm);
    gemm_softmax<<<NB, 512, 0, stream>>>(xu, W, cosm, sinm, target,
                                         rowpart, tgtl, full_mode);
    reduce_rows<<<32, 512, 0, stream>>>(rowpart, rowsum, ng);
    finalize<<<1, 512, 0, stream>>>(rowsum, tgtl, gterm, out);
}

// Round 5
// 382.424 us; speedup vs baseline: 3.3136x; 1.2594x over previous
//
#include <hip/hip_runtime.h>

// ---------------- constants ----------------
#define B_SZ   512
#define K_SZ   512
#define N_CLS  100000
#define NB     1563          // (N_CLS+63)/64 column panels
#define NGRP   128           // fallback grouped-partial slots
#define SCALE_ 64.0f
#define MSLOPE 0.0035f       // (0.8-0.45)/(110-10)
#define L_A_   10.0f
#define U_A_   110.0f

typedef unsigned short u16;
typedef short bf16x8 __attribute__((ext_vector_type(8)));
typedef float f32x4 __attribute__((ext_vector_type(4)));
typedef u16   u16x4 __attribute__((ext_vector_type(4)));

static __device__ inline u16 f2bf(float f) {
    unsigned int u = __float_as_uint(f);
    unsigned int r = (u + 0x7FFFu + ((u >> 16) & 1u)) >> 16;  // RNE
    return (u16)r;
}

static __device__ inline void gl_lds16(const void* g, void* l) {
    __builtin_amdgcn_global_load_lds(
        (const __attribute__((address_space(1))) void*)g,
        (__attribute__((address_space(3))) void*)l, 16, 0, 0);
}

// ---------------- kernel A: per-row prep ----------------
__global__ __launch_bounds__(256) void prep_x(
    const float* __restrict__ x, u16* __restrict__ xu,
    float* __restrict__ cosm, float* __restrict__ sinm,
    float* __restrict__ gterm)
{
    int b = blockIdx.x;
    int tid = threadIdx.x;  // 256 threads, 2 elems each
    float v0 = x[b * K_SZ + tid];
    float v1 = x[b * K_SZ + 256 + tid];
    float s = v0 * v0 + v1 * v1;
    #pragma unroll
    for (int off = 32; off; off >>= 1) s += __shfl_down(s, off);
    __shared__ float red[4];
    if ((tid & 63) == 0) red[tid >> 6] = s;
    __syncthreads();
    float tot = red[0] + red[1] + red[2] + red[3];
    float norm = sqrtf(tot);
    float inv = 1.0f / norm;              // x_unit uses UNclamped norm
    xu[b * K_SZ + tid]       = f2bf(v0 * inv);
    xu[b * K_SZ + 256 + tid] = f2bf(v1 * inv);
    if (tid == 0) {
        float cl = fminf(fmaxf(norm, L_A_), U_A_);   // clamped norm
        float ada = MSLOPE * (cl - L_A_) + 0.45f;
        cosm[b] = cosf(ada);
        sinm[b] = sinf(ada);
        gterm[b] = cl * (1.0f / (U_A_ * U_A_)) + 1.0f / cl;
    }
}

// ---------------- kernel B: fused GEMM + wnorm + margin + partial sumexp ----
// BM=512 (whole batch) x BN=64 cols, BK=32, 8 waves (wave = 64 rows).
// A staged coalesced: wave-inst = 16 rows x 64B full lines; LDS dest linear
// (global_load_lds constraint); k-slot XOR swizzle applied on the GLOBAL
// source so swizzled ds_read_b128 fragment reads are ~2-way (free).
// W read once; per-column sum(w^2) fused into B reg-staging.
// NO min-waves clause: LDS (74.5KB) bounds at 2 blocks/CU anyway; capping
// regs at 128 spilled acc[4][4] (round 4: 187MB scratch writes).
__global__ __launch_bounds__(512) void gemm_softmax(
    const u16* __restrict__ xu, const float* __restrict__ W,
    const float* __restrict__ cosm, const float* __restrict__ sinm,
    const int* __restrict__ target,
    float* __restrict__ rowpart, float* __restrict__ tgtl, int full_mode)
{
    __shared__ u16 As[2][512][32];     // 64 KB (buf, row, 4 slots x 8 bf16)
    __shared__ u16 Bb[2][4][64][8];    // 8 KB  (buf, k_oct, col, 8k)
    __shared__ float sumsq_s[64];
    __shared__ float invw_s[64];
    __shared__ float rowbuf[512];

    const int tid  = threadIdx.x;
    const int lane = tid & 63;
    const int wid  = tid >> 6;          // 0..7
    const int n0   = blockIdx.x * 64;

    // B staging mapping: col = lane, ko = wid&3, jh = wid>>2
    const int bko = wid & 3;
    const int bjh = wid >> 2;
    const int gcol = min(n0 + lane, N_CLS - 1);
    const float* wp = W + (size_t)(bko * 8 + bjh * 4) * N_CLS + (size_t)gcol;

    // A staging mapping: inst i covers rows wid*64+i*16 .. +15 (4 lanes/row)
    const int arow = lane >> 2;         // row within 16-row group
    const int aslot = lane & 3;         // 16B slot within row

    // fragment mapping
    const int sel = lane & 15, fko = lane >> 4;

    float ss = 0.f;
    f32x4 acc[4][4] = {};

    // ---------- prologue: stage kt=0 into buf 0 ----------
    {
        #pragma unroll
        for (int i = 0; i < 4; ++i) {
            int row = wid * 64 + i * 16 + arow;
            int ko  = aslot ^ ((row >> 1) & 3);      // inverse swizzle on src
            gl_lds16(xu + (size_t)row * K_SZ + ko * 8,
                     &As[0][wid * 64 + i * 16][0]);
        }
        float bv[4];
        #pragma unroll
        for (int j = 0; j < 4; ++j) bv[j] = wp[(size_t)j * N_CLS];
        u16x4 bw;
        #pragma unroll
        for (int j = 0; j < 4; ++j) { ss += bv[j] * bv[j]; bw[j] = f2bf(bv[j]); }
        *reinterpret_cast<u16x4*>(&Bb[0][bko][lane][bjh * 4]) = bw;
    }
    __syncthreads();

    // ---------- main loop ----------
    for (int kt = 0; kt < 16; ++kt) {
        const int cur = kt & 1, nxt = cur ^ 1;
        float bv[4];
        if (kt < 15) {
            // issue longest-latency loads first: W (HBM), then A (L2)
            #pragma unroll
            for (int j = 0; j < 4; ++j)
                bv[j] = wp[(size_t)((kt + 1) * 32 + j) * N_CLS];
            #pragma unroll
            for (int i = 0; i < 4; ++i) {
                int row = wid * 64 + i * 16 + arow;
                int ko  = aslot ^ ((row >> 1) & 3);
                gl_lds16(xu + (size_t)row * K_SZ + (kt + 1) * 32 + ko * 8,
                         &As[nxt][wid * 64 + i * 16][0]);
            }
        }

        // MFMA on current buffers
        {
            bf16x8 a[4], b[4];
            #pragma unroll
            for (int m = 0; m < 4; ++m) {
                int row = wid * 64 + m * 16 + sel;
                int s = fko ^ ((row >> 1) & 3);
                a[m] = *reinterpret_cast<const bf16x8*>(&As[cur][row][s * 8]);
            }
            #pragma unroll
            for (int n = 0; n < 4; ++n)
                b[n] = *reinterpret_cast<const bf16x8*>(
                    &Bb[cur][fko][n * 16 + sel][0]);
            #pragma unroll
            for (int m = 0; m < 4; ++m)
                #pragma unroll
                for (int n = 0; n < 4; ++n)
                    acc[m][n] = __builtin_amdgcn_mfma_f32_16x16x32_bf16(
                        a[m], b[n], acc[m][n], 0, 0, 0);
        }

        if (kt < 15) {
            u16x4 bw;
            #pragma unroll
            for (int j = 0; j < 4; ++j) { ss += bv[j] * bv[j]; bw[j] = f2bf(bv[j]); }
            *reinterpret_cast<u16x4*>(&Bb[nxt][bko][lane][bjh * 4]) = bw;
        }
        __syncthreads();
    }

    // ---------- per-column inv norm ----------
    if (tid < 64) sumsq_s[tid] = 0.f;
    __syncthreads();
    atomicAdd(&sumsq_s[lane], ss);      // LDS atomics, 8 threads/col
    __syncthreads();
    if (tid < 64) invw_s[tid] = rsqrtf(sumsq_s[tid]);
    __syncthreads();

    // ---------- epilogue: margin + exp + row partial sums ----------
    const int cloc = lane & 15;
    const int rgrp = lane >> 4;
    float iw[4]; int cols[4];
    #pragma unroll
    for (int n = 0; n < 4; ++n) {
        cols[n] = n0 + n * 16 + cloc;
        iw[n] = invw_s[n * 16 + cloc];
    }
    #pragma unroll
    for (int m = 0; m < 4; ++m) {
        #pragma unroll
        for (int j = 0; j < 4; ++j) {
            int row = wid * 64 + m * 16 + rgrp * 4 + j;
            float cm = cosm[row], smv = sinm[row];
            int tg = target[row];
            float s = 0.f;
            #pragma unroll
            for (int n = 0; n < 4; ++n) {
                if (cols[n] < N_CLS) {
                    float cosv = acc[m][n][j] * iw[n];
                    cosv = fminf(fmaxf(cosv, -1.f), 1.f);
                    float logit = SCALE_ * cosv;
                    if (cols[n] == tg) {
                        float st = sqrtf(fmaxf(0.f, 1.f - cosv * cosv));
                        float cmm = (cosv > 0.f) ? (cosv * cm - st * smv) : cosv;
                        logit = SCALE_ * cmm;
                        tgtl[row] = logit;   // unique writer per row
                    }
                    s += __expf(logit - SCALE_);
                }
            }
            #pragma unroll
            for (int off = 1; off < 16; off <<= 1) s += __shfl_xor(s, off);
            if (cloc == 0) rowbuf[row] = s;
        }
    }
    __syncthreads();
    if (full_mode) {
        rowpart[(size_t)blockIdx.x * B_SZ + tid] = rowbuf[tid];
    } else {
        atomicAdd(&rowpart[(size_t)(blockIdx.x & (NGRP - 1)) * B_SZ + tid],
                  rowbuf[tid]);
    }
}

// ---------------- kernel C: reduce row partials ----------------
__global__ __launch_bounds__(512) void reduce_rows(
    const float* __restrict__ rowpart, float* __restrict__ rowsum, int ng)
{
    int row = threadIdx.x;
    int chunk = (ng + 31) / 32;
    int b0 = blockIdx.x * chunk;
    int b1 = min(b0 + chunk, ng);
    float s = 0.f;
    for (int b = b0; b < b1; ++b)
        s += rowpart[(size_t)b * B_SZ + row];
    atomicAdd(&rowsum[row], s);   // 32 atomics/row, well spread
}

// ---------------- kernel D: finalize ----------------
__global__ __launch_bounds__(512) void finalize(
    const float* __restrict__ rowsum, const float* __restrict__ tgtl,
    const float* __restrict__ gterm, float* __restrict__ out)
{
    int tid = threadIdx.x;
    float v = 0.f;
    if (tid < B_SZ) {
        float ce = SCALE_ + logf(rowsum[tid]) - tgtl[tid];
        v = ce + 20.f * gterm[tid];
    }
    #pragma unroll
    for (int off = 32; off; off >>= 1) v += __shfl_down(v, off);
    __shared__ float red[8];
    if ((tid & 63) == 0) red[tid >> 6] = v;
    __syncthreads();
    if (tid == 0) {
        float t = 0.f;
        #pragma unroll
        for (int i = 0; i < 8; ++i) t += red[i];
        out[0] = t / (float)B_SZ;
    }
}

// ---------------- launch ----------------
extern "C" void kernel_launch(void* const* d_in, const int* in_sizes, int n_in,
                              void* d_out, int out_size, void* d_ws, size_t ws_size,
                              hipStream_t stream)
{
    const float* x      = (const float*)d_in[0];
    const int*   target = (const int*)d_in[1];
    const float* W      = (const float*)d_in[2];
    float* out = (float*)d_out;

    char* ws = (char*)d_ws;
    u16*   xu      = (u16*)(ws);                    // 512*512*2 = 524288
    float* cosm    = (float*)(ws + 524288);
    float* sinm    = (float*)(ws + 526336);
    float* gterm   = (float*)(ws + 528384);
    float* tgtl    = (float*)(ws + 530432);
    float* rowsum  = (float*)(ws + 532480);
    float* rowpart = (float*)(ws + 534528);
    const size_t need_full = 534528 + (size_t)NB * B_SZ * 4;

    int full_mode = (ws_size >= need_full) ? 1 : 0;
    int ng = full_mode ? NB : NGRP;

    hipMemsetAsync(rowsum, 0, B_SZ * sizeof(float), stream);
    if (!full_mode)
        hipMemsetAsync(rowpart, 0, (size_t)NGRP * B_SZ * sizeof(float), stream);

    prep_x<<<B_SZ, 256, 0, stream>>>(x, xu, cosm, sinm, gterm);
    gemm_softmax<<<NB, 512, 0, stream>>>(xu, W, cosm, sinm, target,
                                         rowpart, tgtl, full_mode);
    reduce_rows<<<32, 512, 0, stream>>>(rowpart, rowsum, ng);
    finalize<<<1, 512, 0, stream>>>(rowsum, tgtl, gterm, out);
}